// Round 3
// baseline (1014.142 us; speedup 1.0000x reference)
//
#include <hip/hip_runtime.h>
#include <math.h>

constexpr int Bn = 32;    // batch
constexpr int Tn = 2048;  // time
constexpr int Hn = 1024;  // decoder hidden
constexpr int An = 512;   // attention dim
constexpr int En = 2048;  // enc_dim

typedef __attribute__((ext_vector_type(8))) _Float16 halfx8;
typedef __attribute__((ext_vector_type(4))) float floatx4;

constexpr float WK_SCALE = 4096.0f;       // keeps Wk's fp16 residual in normal range
constexpr float WK_INV   = 1.0f / 4096.0f;

__device__ __forceinline__ unsigned short f2h_bits(float x) {
  _Float16 h = (_Float16)x;               // v_cvt_f16_f32, RNE
  return __builtin_bit_cast(unsigned short, h);
}

// async global->LDS, 16 B per lane; lds must be wave-uniform base (HW adds lane*16)
__device__ __forceinline__ void gload_lds16(const void* g, void* lds) {
  __builtin_amdgcn_global_load_lds(
      (const __attribute__((address_space(1))) unsigned int*)g,
      (__attribute__((address_space(3))) unsigned int*)lds, 16, 0, 0);
}

// ---------------------------------------------------------------------------
// K0a: Wk [A,En] fp32 -> fp16 hi/lo, scaled by 4096. 1M elems.
// ---------------------------------------------------------------------------
__global__ void wk_prep(const float* __restrict__ Wk,
                        unsigned short* __restrict__ wkh,
                        unsigned short* __restrict__ wkl) {
  const int lin = blockIdx.x * 256 + threadIdx.x;   // float4 units, 0..262143
  float4 v = ((const float4*)Wk)[lin];
  ushort4 h, l;
  float s, hf;
  s = v.x * WK_SCALE; h.x = f2h_bits(s); hf = (float)__builtin_bit_cast(_Float16, h.x); l.x = f2h_bits(s - hf);
  s = v.y * WK_SCALE; h.y = f2h_bits(s); hf = (float)__builtin_bit_cast(_Float16, h.y); l.y = f2h_bits(s - hf);
  s = v.z * WK_SCALE; h.z = f2h_bits(s); hf = (float)__builtin_bit_cast(_Float16, h.z); l.z = f2h_bits(s - hf);
  s = v.w * WK_SCALE; h.w = f2h_bits(s); hf = (float)__builtin_bit_cast(_Float16, h.w); l.w = f2h_bits(s - hf);
  ((ushort4*)wkh)[lin] = h;
  ((ushort4*)wkl)[lin] = l;
}

// ---------------------------------------------------------------------------
// K0b: enc [B,T,En] fp32 -> fp16 (single precision copy for the energy GEMM;
// the GEMM previously converted in-kernel, so this is numerically identical).
// 134M elems. Grid-stride, 2048 blocks.
// ---------------------------------------------------------------------------
__global__ __launch_bounds__(256)
void enc_prep(const float* __restrict__ enc, unsigned short* __restrict__ enc16) {
  const size_t total4 = (size_t)Bn * Tn * En / 4;   // float4 units
  const size_t stride = (size_t)gridDim.x * 256;
  for (size_t lin = (size_t)blockIdx.x * 256 + threadIdx.x; lin < total4; lin += stride) {
    float4 v = ((const float4*)enc)[lin];
    ushort4 h;
    h.x = f2h_bits(v.x); h.y = f2h_bits(v.y);
    h.z = f2h_bits(v.z); h.w = f2h_bits(v.w);
    ((ushort4*)enc16)[lin] = h;
  }
}

// ---------------------------------------------------------------------------
// K1: query[b,a] = relu(dec[b,:]·Wq[a,:] + bq[a]); zeroes energy (att slot).
// ---------------------------------------------------------------------------
__global__ void query_kernel(const float* __restrict__ dec,
                             const float* __restrict__ Wq,
                             const float* __restrict__ bq,
                             float* __restrict__ qbuf,
                             float* __restrict__ energy_zero) {
  __shared__ float sdec[Hn];
  const int b = blockIdx.x;
  const int gl = (blockIdx.y * 32 + blockIdx.x) * 128 + threadIdx.x;
  ((float4*)energy_zero)[gl] = make_float4(0.f, 0.f, 0.f, 0.f);

  for (int i = threadIdx.x; i < Hn; i += blockDim.x) sdec[i] = dec[b * Hn + i];
  __syncthreads();
  const int a = blockIdx.y * 128 + threadIdx.x;
  const float* w = Wq + (size_t)a * Hn;
  float acc = 0.f;
  #pragma unroll 4
  for (int k = 0; k < Hn; k += 4) {
    float4 wv = *(const float4*)(w + k);
    acc = fmaf(wv.x, sdec[k + 0], acc);
    acc = fmaf(wv.y, sdec[k + 1], acc);
    acc = fmaf(wv.z, sdec[k + 2], acc);
    acc = fmaf(wv.w, sdec[k + 3], acc);
  }
  qbuf[b * An + a] = fmaxf(acc + bq[a], 0.f);
}

// ---------------------------------------------------------------------------
// K2: fp16 2-MFMA energy GEMM. C = enc16 · (Wk_hi + Wk_lo)^T (Wk scaled 4096)
// energy[row] += sum_a relu(C*(1/4096) + bk[a]) * q[b,a]
// Block 128 rows x 256 a, BK=64. 4 waves 2x2, wave tile 64x128 (4x8 of
// 16x16x32_f16, 2 MFMAs each). LDS: sA 16 KB + sB hi/lo 64 KB = 80 KB
// -> 2 blocks/CU. BOTH A and B staged via global_load_lds width=16 with
// pre-swizzled global source (linear LDS dest, m173 pattern) — no VALU
// convert, no ds_write in the K-loop.
// ---------------------------------------------------------------------------
__global__ __launch_bounds__(256, 2)
void energy_kernel(const unsigned short* __restrict__ enc16,
                   const unsigned short* __restrict__ wkh,
                   const unsigned short* __restrict__ wkl,
                   const float* __restrict__ bk,
                   const float* __restrict__ qbuf,
                   float* __restrict__ energy) {
  __shared__ unsigned short sA[128 * 64];    // fp16 enc tile   (16 KB)
  __shared__ unsigned short sBh[256 * 64];   // fp16 Wk hi tile (32 KB)
  __shared__ unsigned short sBl[256 * 64];   // fp16 Wk lo tile (32 KB)

  const int tid = threadIdx.x;
  const int lane = tid & 63;
  const int wid = tid >> 6;
  const int wr = wid >> 1, wc = wid & 1;     // wave grid 2x2 (n-major inner)
  const int lr = lane & 15, lq = lane >> 4;

  const int nblk = blockIdx.x & 1;           // n-pairs adjacent -> L3 enc reuse
  const long row_base = (long)(blockIdx.x >> 1) * 128;
  const int n_base = nblk * 256;
  const int b = (int)(row_base >> 11);

  floatx4 acc[4][8];
  #pragma unroll
  for (int i = 0; i < 4; ++i)
    #pragma unroll
    for (int j = 0; j < 8; ++j) acc[i][j] = (floatx4){0.f, 0.f, 0.f, 0.f};

  for (int k0 = 0; k0 < En; k0 += 64) {
    // --- stage A via global_load_lds: slot s holds k-chunk (s&7)^(row&7) of
    // row s>>3 (chunk = 16 B = 8 fp16). 1024 slots, 4 waves x 4 iters x 64.
    #pragma unroll
    for (int it = 0; it < 4; ++it) {
      const int sidx = wid * 256 + it * 64 + lane;
      const int row = sidx >> 3;
      const int c = (sidx & 7) ^ (row & 7);
      const size_t goff = (row_base + row) * En + k0 + c * 8;
      gload_lds16(enc16 + goff, &sA[(wid * 256 + it * 64) * 8]);
    }
    // --- stage B via global_load_lds: slot gidx holds chunk (gidx&7)^(a&7)
    // wave 'wid' stages gidx in [wid*512, wid*512+512), 8 iters of 64 lanes.
    #pragma unroll
    for (int it = 0; it < 8; ++it) {
      const int gidx = wid * 512 + it * 64 + lane;
      const int a = gidx >> 3;
      const int c = (gidx & 7) ^ (a & 7);
      const size_t goff = (size_t)(n_base + a) * En + k0 + c * 8;
      unsigned short* ldsb_h = &sBh[(wid * 512 + it * 64) * 8];
      unsigned short* ldsb_l = &sBl[(wid * 512 + it * 64) * 8];
      gload_lds16(wkh + goff, ldsb_h);
      gload_lds16(wkl + goff, ldsb_l);
    }
    __syncthreads();

    #pragma unroll
    for (int ks = 0; ks < 2; ++ks) {
      const int cb = ks * 4 + lq;                // k-chunk this quad consumes
      halfx8 ah[4];
      #pragma unroll
      for (int mt = 0; mt < 4; ++mt) {
        const int m = wr * 64 + mt * 16 + lr;
        ah[mt] = *(const halfx8*)&sA[m * 64 + ((cb ^ (m & 7)) << 3)];
      }
      #pragma unroll
      for (int ng = 0; ng < 2; ++ng) {           // split n-tiles to cap registers
        halfx8 bh[4], bl[4];
        #pragma unroll
        for (int nt = 0; nt < 4; ++nt) {
          const int n = wc * 128 + (ng * 4 + nt) * 16 + lr;
          const int off = n * 64 + ((cb ^ (n & 7)) << 3);
          bh[nt] = *(const halfx8*)&sBh[off];
          bl[nt] = *(const halfx8*)&sBl[off];
        }
        #pragma unroll
        for (int mt = 0; mt < 4; ++mt)
          #pragma unroll
          for (int nt = 0; nt < 4; ++nt) {
            acc[mt][ng * 4 + nt] = __builtin_amdgcn_mfma_f32_16x16x32_f16(ah[mt], bl[nt], acc[mt][ng * 4 + nt], 0, 0, 0);
            acc[mt][ng * 4 + nt] = __builtin_amdgcn_mfma_f32_16x16x32_f16(ah[mt], bh[nt], acc[mt][ng * 4 + nt], 0, 0, 0);
          }
      }
    }
    __syncthreads();
  }

  // --- epilogue: relu(C/4096 + bk)*q over 256 a-cols; C/D: col=lane&15,
  // row=(lane>>4)*4+reg  [m89]
  float bkv[8], qv[8];
  #pragma unroll
  for (int nt = 0; nt < 8; ++nt) {
    const int ncol = n_base + wc * 128 + nt * 16 + lr;
    bkv[nt] = bk[ncol];
    qv[nt] = qbuf[b * An + ncol];
  }
  #pragma unroll
  for (int mt = 0; mt < 4; ++mt) {
    #pragma unroll
    for (int r = 0; r < 4; ++r) {
      float s = 0.f;
      #pragma unroll
      for (int nt = 0; nt < 8; ++nt)
        s = fmaf(fmaxf(fmaf(acc[mt][nt][r], WK_INV, bkv[nt]), 0.f), qv[nt], s);
      s += __shfl_xor(s, 1, 64);
      s += __shfl_xor(s, 2, 64);
      s += __shfl_xor(s, 4, 64);
      s += __shfl_xor(s, 8, 64);
      if (lr == 0) {
        const long row = row_base + wr * 64 + mt * 16 + lq * 4 + r;
        atomicAdd(&energy[row], s);
      }
    }
  }
}

// ---------------------------------------------------------------------------
// K3: softmax over T with mask renorm + COMPACTION: block b owns batch b,
// appends (t, w) for w > 1e-7 to list[b] (dropped mass <= 2048e-7 -> err ~1e-3).
// ---------------------------------------------------------------------------
__global__ void softmax_kernel(float* __restrict__ att,
                               const float* __restrict__ mask,
                               uint2* __restrict__ list,
                               unsigned* __restrict__ cnt) {
  const int b = blockIdx.x;
  const int tid = threadIdx.x;
  const int lane = tid & 63;
  const int wave = tid >> 6;
  __shared__ float wred[4];
  __shared__ unsigned cnt_l;
  if (tid == 0) cnt_l = 0;

  float e[8];
  float m = -INFINITY;
  #pragma unroll
  for (int i = 0; i < 8; ++i) {
    e[i] = att[b * Tn + tid + i * 256];
    m = fmaxf(m, e[i]);
  }
  #pragma unroll
  for (int off = 32; off > 0; off >>= 1) m = fmaxf(m, __shfl_xor(m, off, 64));
  if (lane == 0) wred[wave] = m;
  __syncthreads();
  m = fmaxf(fmaxf(wred[0], wred[1]), fmaxf(wred[2], wred[3]));
  __syncthreads();

  float p[8];
  float s = 0.f;
  #pragma unroll
  for (int i = 0; i < 8; ++i) {
    p[i] = expf(e[i] - m) * mask[b * Tn + tid + i * 256];
    s += p[i];
  }
  #pragma unroll
  for (int off = 32; off > 0; off >>= 1) s += __shfl_xor(s, off, 64);
  if (lane == 0) wred[wave] = s;
  __syncthreads();
  const float inv = 1.f / (wred[0] + wred[1] + wred[2] + wred[3]);
  #pragma unroll
  for (int i = 0; i < 8; ++i) {
    const int t = tid + i * 256;
    const float w = p[i] * inv;
    att[b * Tn + t] = w;
    if (w > 1e-7f) {
      unsigned pos = atomicAdd(&cnt_l, 1u);
      list[b * Tn + pos] = make_uint2((unsigned)t, __float_as_uint(w));
    }
  }
  __syncthreads();
  if (tid == 0) cnt[b] = cnt_l;
}

// ---------------------------------------------------------------------------
// K4: context[b,e] = sum over compacted list of w * enc[b,t,e].
// grid (2 e-chunks, 32 b); block 256, float4/thread; block-owned -> plain store.
// ---------------------------------------------------------------------------
__global__ void context_kernel(const float* __restrict__ enc,
                               const uint2* __restrict__ list,
                               const unsigned* __restrict__ cnt,
                               float* __restrict__ ctx) {
  const int ec = blockIdx.x, b = blockIdx.y;
  const int tid = threadIdx.x;
  __shared__ uint2 slist[Tn];
  const int n = (int)cnt[b];
  for (int j = tid; j < n; j += 256) slist[j] = list[b * Tn + j];
  __syncthreads();

  const int e0 = ec * 1024 + tid * 4;
  const float* base = enc + (size_t)b * Tn * En + e0;
  float4 a0 = make_float4(0, 0, 0, 0), a1 = a0, a2 = a0, a3 = a0;
  int j = 0;
  for (; j + 4 <= n; j += 4) {
    uint2 p0 = slist[j], p1 = slist[j + 1], p2 = slist[j + 2], p3 = slist[j + 3];
    float4 v0 = *(const float4*)(base + (size_t)p0.x * En);
    float4 v1 = *(const float4*)(base + (size_t)p1.x * En);
    float4 v2 = *(const float4*)(base + (size_t)p2.x * En);
    float4 v3 = *(const float4*)(base + (size_t)p3.x * En);
    const float w0 = __uint_as_float(p0.y), w1 = __uint_as_float(p1.y);
    const float w2 = __uint_as_float(p2.y), w3 = __uint_as_float(p3.y);
    a0.x = fmaf(w0, v0.x, a0.x); a0.y = fmaf(w0, v0.y, a0.y); a0.z = fmaf(w0, v0.z, a0.z); a0.w = fmaf(w0, v0.w, a0.w);
    a1.x = fmaf(w1, v1.x, a1.x); a1.y = fmaf(w1, v1.y, a1.y); a1.z = fmaf(w1, v1.z, a1.z); a1.w = fmaf(w1, v1.w, a1.w);
    a2.x = fmaf(w2, v2.x, a2.x); a2.y = fmaf(w2, v2.y, a2.y); a2.z = fmaf(w2, v2.z, a2.z); a2.w = fmaf(w2, v2.w, a2.w);
    a3.x = fmaf(w3, v3.x, a3.x); a3.y = fmaf(w3, v3.y, a3.y); a3.z = fmaf(w3, v3.z, a3.z); a3.w = fmaf(w3, v3.w, a3.w);
  }
  for (; j < n; ++j) {
    uint2 p0 = slist[j];
    float4 v0 = *(const float4*)(base + (size_t)p0.x * En);
    const float w0 = __uint_as_float(p0.y);
    a0.x = fmaf(w0, v0.x, a0.x); a0.y = fmaf(w0, v0.y, a0.y); a0.z = fmaf(w0, v0.z, a0.z); a0.w = fmaf(w0, v0.w, a0.w);
  }
  a0.x += a1.x + a2.x + a3.x; a0.y += a1.y + a2.y + a3.y;
  a0.z += a1.z + a2.z + a3.z; a0.w += a1.w + a2.w + a3.w;
  *(float4*)(ctx + b * En + e0) = a0;
}

// ---------------------------------------------------------------------------
extern "C" void kernel_launch(void* const* d_in, const int* in_sizes, int n_in,
                              void* d_out, int out_size, void* d_ws, size_t ws_size,
                              hipStream_t stream) {
  const float* enc  = (const float*)d_in[0];
  const float* dec  = (const float*)d_in[1];
  const float* mask = (const float*)d_in[2];
  const float* Wq   = (const float*)d_in[3];
  const float* bq   = (const float*)d_in[4];
  const float* Wk   = (const float*)d_in[5];
  const float* bk   = (const float*)d_in[6];

  float* out = (float*)d_out;
  float* att = out;                // output 0: attention [B,1,T]
  float* ctx = out + Bn * Tn;      // output 1: context  [B,En]

  // ws layout: enc16 (256MB) | wkh (2MB) | wkl (2MB) | qbuf (64KB) | cnt | list
  unsigned short* enc16 = (unsigned short*)d_ws;
  unsigned short* wkh = enc16 + (size_t)Bn * Tn * En;
  unsigned short* wkl = wkh + (size_t)An * En;
  float* qbuf = (float*)(wkl + (size_t)An * En);
  unsigned* cnt = (unsigned*)(qbuf + Bn * An);
  uint2* list = (uint2*)(cnt + 32);

  wk_prep<<<(An * En) / (256 * 4), 256, 0, stream>>>(Wk, wkh, wkl);
  enc_prep<<<2048, 256, 0, stream>>>(enc, enc16);
  query_kernel<<<dim3(Bn, 4), 128, 0, stream>>>(dec, Wq, bq, qbuf, att);
  energy_kernel<<<(Bn * Tn / 128) * 2, 256, 0, stream>>>(enc16, wkh, wkl, bk, qbuf, att);
  softmax_kernel<<<Bn, 256, 0, stream>>>(att, mask, list, cnt);
  context_kernel<<<dim3(2, Bn), 256, 0, stream>>>(enc, list, cnt, ctx);
}

// Round 4
// 891.869 us; speedup vs baseline: 1.1371x; 1.1371x over previous
//
#include <hip/hip_runtime.h>
#include <math.h>

constexpr int Bn = 32;    // batch
constexpr int Tn = 2048;  // time
constexpr int Hn = 1024;  // decoder hidden
constexpr int An = 512;   // attention dim
constexpr int En = 2048;  // enc_dim

typedef __attribute__((ext_vector_type(8))) _Float16 halfx8;
typedef __attribute__((ext_vector_type(4))) float floatx4;

constexpr float WK_SCALE = 4096.0f;       // keeps Wk's fp16 residual in normal range
constexpr float WK_INV   = 1.0f / 4096.0f;

__device__ __forceinline__ unsigned short f2h_bits(float x) {
  _Float16 h = (_Float16)x;               // v_cvt_f16_f32, RNE
  return __builtin_bit_cast(unsigned short, h);
}

// async global->LDS, 16 B per lane; lds must be wave-uniform base (HW adds lane*16)
__device__ __forceinline__ void gload_lds16(const void* g, void* lds) {
  __builtin_amdgcn_global_load_lds(
      (const __attribute__((address_space(1))) unsigned int*)g,
      (__attribute__((address_space(3))) unsigned int*)lds, 16, 0, 0);
}

// ---------------------------------------------------------------------------
// K0: Wk [A,En] fp32 -> fp16 hi/lo, scaled by 4096. 1M elems.
// ---------------------------------------------------------------------------
__global__ void wk_prep(const float* __restrict__ Wk,
                        unsigned short* __restrict__ wkh,
                        unsigned short* __restrict__ wkl) {
  const int lin = blockIdx.x * 256 + threadIdx.x;   // float4 units, 0..262143
  float4 v = ((const float4*)Wk)[lin];
  ushort4 h, l;
  float s, hf;
  s = v.x * WK_SCALE; h.x = f2h_bits(s); hf = (float)__builtin_bit_cast(_Float16, h.x); l.x = f2h_bits(s - hf);
  s = v.y * WK_SCALE; h.y = f2h_bits(s); hf = (float)__builtin_bit_cast(_Float16, h.y); l.y = f2h_bits(s - hf);
  s = v.z * WK_SCALE; h.z = f2h_bits(s); hf = (float)__builtin_bit_cast(_Float16, h.z); l.z = f2h_bits(s - hf);
  s = v.w * WK_SCALE; h.w = f2h_bits(s); hf = (float)__builtin_bit_cast(_Float16, h.w); l.w = f2h_bits(s - hf);
  ((ushort4*)wkh)[lin] = h;
  ((ushort4*)wkl)[lin] = l;
}

// ---------------------------------------------------------------------------
// K1: query[b,a] = relu(dec[b,:]·Wq[a,:] + bq[a]); zeroes energy (att slot).
// grid (32 b, 8 a-groups) x 256 thr; thread quads split K in 4 -> full CU
// coverage (256 blocks vs old 128) and 4x shorter dependent-FMA chain.
// ---------------------------------------------------------------------------
__global__ __launch_bounds__(256)
void query_kernel(const float* __restrict__ dec,
                  const float* __restrict__ Wq,
                  const float* __restrict__ bq,
                  float* __restrict__ qbuf,
                  float* __restrict__ energy_zero) {
  __shared__ float sdec[Hn];
  const int b = blockIdx.x;          // 0..31
  const int ag = blockIdx.y;         // 0..7, a-group of 64
  const int tid = threadIdx.x;
  energy_zero[(blockIdx.y * 32 + blockIdx.x) * 256 + tid] = 0.f;

  for (int i = tid; i < Hn; i += 256) sdec[i] = dec[b * Hn + i];
  __syncthreads();
  const int a = ag * 64 + (tid >> 2);
  const int kq = tid & 3;            // K-quarter 0..3
  const float* w = Wq + (size_t)a * Hn + kq * 256;
  const float* sd = sdec + kq * 256;
  float acc = 0.f;
  #pragma unroll 4
  for (int k = 0; k < 256; k += 4) {
    float4 wv = *(const float4*)(w + k);
    acc = fmaf(wv.x, sd[k + 0], acc);
    acc = fmaf(wv.y, sd[k + 1], acc);
    acc = fmaf(wv.z, sd[k + 2], acc);
    acc = fmaf(wv.w, sd[k + 3], acc);
  }
  acc += __shfl_xor(acc, 1, 64);
  acc += __shfl_xor(acc, 2, 64);
  if (kq == 0) qbuf[b * An + a] = fmaxf(acc + bq[a], 0.f);
}

// ---------------------------------------------------------------------------
// K2: fp16 2-MFMA energy GEMM. C = enc_h16 · (Wk_hi + Wk_lo)^T (Wk scaled 4096)
// energy[row] += sum_a relu(C*(1/4096) + bk[a]) * q[b,a]
// Block 128 rows x 128 a, BK=64. 4 waves 2x2, wave tile 64x64 (4x4 of
// 16x16x32_f16, 2 MFMAs each). LDS: sA 16 KB + sB hi/lo 32 KB = 48 KB
// -> 3 blocks/CU (12 waves, m97-class occupancy; was 80 KB -> 2 blocks).
// acc 64 VGPR (was 128) + __launch_bounds__(256,3) keeps VGPR <= 170.
// Grid 2048: bid = xcd + 8*(nblk + 4*gh); the 4 n-siblings of a row tile
// share one XCD's L2 (bijective remap, perf-only).
// ---------------------------------------------------------------------------
__global__ __launch_bounds__(256, 3)
void energy_kernel(const float* __restrict__ enc,
                   const unsigned short* __restrict__ wkh,
                   const unsigned short* __restrict__ wkl,
                   const float* __restrict__ bk,
                   const float* __restrict__ qbuf,
                   float* __restrict__ energy) {
  __shared__ unsigned short sA[128 * 64];    // fp16 enc tile   (16 KB)
  __shared__ unsigned short sBh[128 * 64];   // fp16 Wk hi tile (16 KB)
  __shared__ unsigned short sBl[128 * 64];   // fp16 Wk lo tile (16 KB)

  const int tid = threadIdx.x;
  const int lane = tid & 63;
  const int wid = tid >> 6;
  const int wr = wid >> 1, wc = wid & 1;     // wave grid 2x2
  const int lr = lane & 15, lq = lane >> 4;

  const int bid = blockIdx.x;
  const int xcd = bid & 7;
  const int rem = bid >> 3;
  const int nblk = rem & 3;                  // n-tile 0..3 (128 cols each)
  const int g = (rem >> 2) * 8 + xcd;        // row tile 0..511
  const long row_base = (long)g * 128;
  const int n_base = nblk * 128;
  const int b = g >> 4;                      // 16 row-tiles per batch

  floatx4 acc[4][4];
  #pragma unroll
  for (int i = 0; i < 4; ++i)
    #pragma unroll
    for (int j = 0; j < 4; ++j) acc[i][j] = (floatx4){0.f, 0.f, 0.f, 0.f};

  for (int k0 = 0; k0 < En; k0 += 64) {
    // --- stage A: 128 rows x 64 k fp32 -> fp16, swizzled 16B chunks.
    // slot s of row holds k-chunk (s ^ (row&7)); here chunk c -> slot c^(row&7).
    #pragma unroll
    for (int rep = 0; rep < 8; ++rep) {
      const int lin = tid + rep * 256;           // 0..2047 float4 units
      const int row = lin >> 4, e4 = lin & 15;   // e4: float4 index (16 floats/row)
      float4 v = *(const float4*)(enc + (row_base + row) * En + k0 + e4 * 4);
      ushort4 h;
      h.x = f2h_bits(v.x); h.y = f2h_bits(v.y);
      h.z = f2h_bits(v.z); h.w = f2h_bits(v.w);
      const int chunk = e4 >> 1, half = e4 & 1;  // chunk = 8 fp16 = 16 B
      const int off = row * 64 + ((chunk ^ (row & 7)) << 3) + (half << 2);
      *(ushort4*)&sA[off] = h;
    }
    // --- stage B via global_load_lds: slot gidx holds chunk (gidx&7)^(a&7)
    // 1024 slots; wave 'wid' stages gidx in [wid*256, wid*256+256), 4 iters.
    #pragma unroll
    for (int it = 0; it < 4; ++it) {
      const int gidx = wid * 256 + it * 64 + lane;
      const int a = gidx >> 3;                   // 0..127
      const int c = (gidx & 7) ^ (a & 7);
      const size_t goff = (size_t)(n_base + a) * En + k0 + c * 8;
      gload_lds16(wkh + goff, &sBh[(wid * 256 + it * 64) * 8]);
      gload_lds16(wkl + goff, &sBl[(wid * 256 + it * 64) * 8]);
    }
    __syncthreads();

    #pragma unroll
    for (int ks = 0; ks < 2; ++ks) {
      const int cb = ks * 4 + lq;                // k-chunk this quad consumes
      halfx8 ah[4];
      #pragma unroll
      for (int mt = 0; mt < 4; ++mt) {
        const int m = wr * 64 + mt * 16 + lr;
        ah[mt] = *(const halfx8*)&sA[m * 64 + ((cb ^ (m & 7)) << 3)];
      }
      halfx8 bh[4], bl[4];
      #pragma unroll
      for (int nt = 0; nt < 4; ++nt) {
        const int n = wc * 64 + nt * 16 + lr;
        const int off = n * 64 + ((cb ^ (n & 7)) << 3);
        bh[nt] = *(const halfx8*)&sBh[off];
        bl[nt] = *(const halfx8*)&sBl[off];
      }
      #pragma unroll
      for (int mt = 0; mt < 4; ++mt)
        #pragma unroll
        for (int nt = 0; nt < 4; ++nt) {
          acc[mt][nt] = __builtin_amdgcn_mfma_f32_16x16x32_f16(ah[mt], bl[nt], acc[mt][nt], 0, 0, 0);
          acc[mt][nt] = __builtin_amdgcn_mfma_f32_16x16x32_f16(ah[mt], bh[nt], acc[mt][nt], 0, 0, 0);
        }
    }
    __syncthreads();
  }

  // --- epilogue: relu(C/4096 + bk)*q over this block's 128 a-cols;
  // C/D: col=lane&15, row=(lane>>4)*4+reg  [m89]
  float bkv[4], qv[4];
  #pragma unroll
  for (int nt = 0; nt < 4; ++nt) {
    const int ncol = n_base + wc * 64 + nt * 16 + lr;
    bkv[nt] = bk[ncol];
    qv[nt] = qbuf[b * An + ncol];
  }
  #pragma unroll
  for (int mt = 0; mt < 4; ++mt) {
    #pragma unroll
    for (int r = 0; r < 4; ++r) {
      float s = 0.f;
      #pragma unroll
      for (int nt = 0; nt < 4; ++nt)
        s = fmaf(fmaxf(fmaf(acc[mt][nt][r], WK_INV, bkv[nt]), 0.f), qv[nt], s);
      s += __shfl_xor(s, 1, 64);
      s += __shfl_xor(s, 2, 64);
      s += __shfl_xor(s, 4, 64);
      s += __shfl_xor(s, 8, 64);
      if (lr == 0) {
        const long row = row_base + wr * 64 + mt * 16 + lq * 4 + r;
        atomicAdd(&energy[row], s);
      }
    }
  }
}

// ---------------------------------------------------------------------------
// K3: softmax over T with mask renorm + COMPACTION: block b owns batch b,
// appends (t, w) for w > 1e-7 to list[b] (dropped mass <= 2048e-7 -> err ~1e-3).
// ---------------------------------------------------------------------------
__global__ void softmax_kernel(float* __restrict__ att,
                               const float* __restrict__ mask,
                               uint2* __restrict__ list,
                               unsigned* __restrict__ cnt) {
  const int b = blockIdx.x;
  const int tid = threadIdx.x;
  const int lane = tid & 63;
  const int wave = tid >> 6;
  __shared__ float wred[4];
  __shared__ unsigned cnt_l;
  if (tid == 0) cnt_l = 0;

  float e[8];
  float m = -INFINITY;
  #pragma unroll
  for (int i = 0; i < 8; ++i) {
    e[i] = att[b * Tn + tid + i * 256];
    m = fmaxf(m, e[i]);
  }
  #pragma unroll
  for (int off = 32; off > 0; off >>= 1) m = fmaxf(m, __shfl_xor(m, off, 64));
  if (lane == 0) wred[wave] = m;
  __syncthreads();
  m = fmaxf(fmaxf(wred[0], wred[1]), fmaxf(wred[2], wred[3]));
  __syncthreads();

  float p[8];
  float s = 0.f;
  #pragma unroll
  for (int i = 0; i < 8; ++i) {
    p[i] = expf(e[i] - m) * mask[b * Tn + tid + i * 256];
    s += p[i];
  }
  #pragma unroll
  for (int off = 32; off > 0; off >>= 1) s += __shfl_xor(s, off, 64);
  if (lane == 0) wred[wave] = s;
  __syncthreads();
  const float inv = 1.f / (wred[0] + wred[1] + wred[2] + wred[3]);
  #pragma unroll
  for (int i = 0; i < 8; ++i) {
    const int t = tid + i * 256;
    const float w = p[i] * inv;
    att[b * Tn + t] = w;
    if (w > 1e-7f) {
      unsigned pos = atomicAdd(&cnt_l, 1u);
      list[b * Tn + pos] = make_uint2((unsigned)t, __float_as_uint(w));
    }
  }
  __syncthreads();
  if (tid == 0) cnt[b] = cnt_l;
}

// ---------------------------------------------------------------------------
// K4: context[b,e] = sum over compacted list of w * enc[b,t,e].
// grid (2 e-chunks, 32 b); block 256, float4/thread; block-owned -> plain store.
// ---------------------------------------------------------------------------
__global__ void context_kernel(const float* __restrict__ enc,
                               const uint2* __restrict__ list,
                               const unsigned* __restrict__ cnt,
                               float* __restrict__ ctx) {
  const int ec = blockIdx.x, b = blockIdx.y;
  const int tid = threadIdx.x;
  __shared__ uint2 slist[Tn];
  const int n = (int)cnt[b];
  for (int j = tid; j < n; j += 256) slist[j] = list[b * Tn + j];
  __syncthreads();

  const int e0 = ec * 1024 + tid * 4;
  const float* base = enc + (size_t)b * Tn * En + e0;
  float4 a0 = make_float4(0, 0, 0, 0), a1 = a0, a2 = a0, a3 = a0;
  int j = 0;
  for (; j + 4 <= n; j += 4) {
    uint2 p0 = slist[j], p1 = slist[j + 1], p2 = slist[j + 2], p3 = slist[j + 3];
    float4 v0 = *(const float4*)(base + (size_t)p0.x * En);
    float4 v1 = *(const float4*)(base + (size_t)p1.x * En);
    float4 v2 = *(const float4*)(base + (size_t)p2.x * En);
    float4 v3 = *(const float4*)(base + (size_t)p3.x * En);
    const float w0 = __uint_as_float(p0.y), w1 = __uint_as_float(p1.y);
    const float w2 = __uint_as_float(p2.y), w3 = __uint_as_float(p3.y);
    a0.x = fmaf(w0, v0.x, a0.x); a0.y = fmaf(w0, v0.y, a0.y); a0.z = fmaf(w0, v0.z, a0.z); a0.w = fmaf(w0, v0.w, a0.w);
    a1.x = fmaf(w1, v1.x, a1.x); a1.y = fmaf(w1, v1.y, a1.y); a1.z = fmaf(w1, v1.z, a1.z); a1.w = fmaf(w1, v1.w, a1.w);
    a2.x = fmaf(w2, v2.x, a2.x); a2.y = fmaf(w2, v2.y, a2.y); a2.z = fmaf(w2, v2.z, a2.z); a2.w = fmaf(w2, v2.w, a2.w);
    a3.x = fmaf(w3, v3.x, a3.x); a3.y = fmaf(w3, v3.y, a3.y); a3.z = fmaf(w3, v3.z, a3.z); a3.w = fmaf(w3, v3.w, a3.w);
  }
  for (; j < n; ++j) {
    uint2 p0 = slist[j];
    float4 v0 = *(const float4*)(base + (size_t)p0.x * En);
    const float w0 = __uint_as_float(p0.y);
    a0.x = fmaf(w0, v0.x, a0.x); a0.y = fmaf(w0, v0.y, a0.y); a0.z = fmaf(w0, v0.z, a0.z); a0.w = fmaf(w0, v0.w, a0.w);
  }
  a0.x += a1.x + a2.x + a3.x; a0.y += a1.y + a2.y + a3.y;
  a0.z += a1.z + a2.z + a3.z; a0.w += a1.w + a2.w + a3.w;
  *(float4*)(ctx + b * En + e0) = a0;
}

// ---------------------------------------------------------------------------
extern "C" void kernel_launch(void* const* d_in, const int* in_sizes, int n_in,
                              void* d_out, int out_size, void* d_ws, size_t ws_size,
                              hipStream_t stream) {
  const float* enc  = (const float*)d_in[0];
  const float* dec  = (const float*)d_in[1];
  const float* mask = (const float*)d_in[2];
  const float* Wq   = (const float*)d_in[3];
  const float* bq   = (const float*)d_in[4];
  const float* Wk   = (const float*)d_in[5];
  const float* bk   = (const float*)d_in[6];

  float* out = (float*)d_out;
  float* att = out;                // output 0: attention [B,1,T]
  float* ctx = out + Bn * Tn;      // output 1: context  [B,En]

  // ws layout: wkh (2MB) | wkl (2MB) | qbuf (64KB) | cnt (128B) | list (512KB)
  unsigned short* wkh = (unsigned short*)d_ws;
  unsigned short* wkl = wkh + (size_t)An * En;
  float* qbuf = (float*)(wkl + (size_t)An * En);
  unsigned* cnt = (unsigned*)(qbuf + Bn * An);
  uint2* list = (uint2*)(cnt + 32);

  wk_prep<<<(An * En) / (256 * 4), 256, 0, stream>>>(Wk, wkh, wkl);
  query_kernel<<<dim3(Bn, 8), 256, 0, stream>>>(dec, Wq, bq, qbuf, att);
  energy_kernel<<<(Bn * Tn / 128) * 4, 256, 0, stream>>>(enc, wkh, wkl, bk, qbuf, att);
  softmax_kernel<<<Bn, 256, 0, stream>>>(att, mask, list, cnt);
  context_kernel<<<dim3(2, Bn), 256, 0, stream>>>(enc, list, cnt, ctx);
}